// Round 2
// baseline (7071.719 us; speedup 1.0000x reference)
//
#include <hip/hip_runtime.h>
#include <math.h>

namespace {

constexpr int B = 8, T = 10, C = 32, H = 128, W = 128;
constexpr int HW = H * W;            // 16384
constexpr int CHW = C * HW;          // 524288
constexpr long long NSTATE = (long long)B * CHW;
constexpr int BHW = B * HW;

constexpr float DF = 0.90483741803595952f;  // exp(-0.1)
constexpr float DL = 0.36787944117144233f;  // exp(-1.0)
constexpr float DE = 0.36787944117144233f;  // exp(-1.0)
constexpr float VE = 10.0f;

// wgt[co][ci][kh][kw] -> wtr[ci][k][co]   (9216 floats)
__global__ void k_wtr(const float* __restrict__ wgt, float* __restrict__ wtr) {
  int i = blockIdx.x * 256 + threadIdx.x;
  if (i >= C * C * 9) return;
  int ci = i / 288;
  int k = (i / 32) % 9;
  int co = i & 31;
  wtr[i] = wgt[co * 288 + ci * 9 + k];
}

__global__ void k_init(float* __restrict__ f, float* __restrict__ l,
                       float* __restrict__ e, float* __restrict__ y,
                       float* __restrict__ s0) {
  long long i = (long long)blockIdx.x * 256 + threadIdx.x;
  f[i] = 0.f;
  l[i] = 0.f;
  y[i] = 0.f;
  e[i] = 10.f;  // V_E / ALPHA_E
  if (i < BHW) s0[i] = 0.f;
}

// One step. Block: 512 threads (8 waves), tile 8 rows x 32 cols, all 32 c_out.
// Wave g owns c_out = 4g..4g+3; lane: sw = strip (8x4px), sh = row (0..7).
// ci processed in 4 chunks of 8, double-buffered LDS (y-tile + weights).
__launch_bounds__(512, 4)
__global__ void k_step(const float* __restrict__ x, const float* __restrict__ wtr,
                       const float* __restrict__ bias,
                       const float* __restrict__ s_in, float* __restrict__ s_out,
                       const float* __restrict__ y_old, long long ybs,
                       float* __restrict__ f, float* __restrict__ l,
                       float* __restrict__ e, float* __restrict__ out, int t) {
  __shared__ float ysl[2][8][10][40];  // [buf][ci][row][slot] slot = w-(w0-4)
  __shared__ float wsl[2][8][9][32];   // [buf][ci][k][c_out]
  __shared__ float sl[10][36];         // channel-sum tile (+halo)
  __shared__ float sred[8][64][4];     // chansum partials

  const int tid = threadIdx.x;
  const int bid = blockIdx.x;
  const int tw = bid & 3, th = (bid >> 2) & 15, b = bid >> 6;
  const int h0 = th * 8, w0 = tw * 32;
  const int g = tid >> 6, sidx = tid & 63;
  const int sw = sidx & 7, sh = sidx >> 3;
  const int cb = sw * 4;
  const int gh = h0 + sh, gwc = w0 + cb;

  auto stage = [&](int cc, int nb) {
    // weights: contiguous 2304-float chunk
    const float4* wsrc = (const float4*)(wtr + cc * 2304);
    float4* wdst = (float4*)&wsl[nb][0][0][0];
    for (int i = tid; i < 576; i += 512) wdst[i] = wsrc[i];
    // y tile: 8 ci x 10 rows x 10 aligned float4 (slots 0..39)
    for (int idx = tid; idx < 800; idx += 512) {
      int cil = idx / 100;
      int rem = idx % 100;
      int rr = rem / 10;
      int j = rem % 10;
      int gh2 = h0 - 1 + rr;
      int ws2 = w0 - 4 + 4 * j;
      float4 v = make_float4(0.f, 0.f, 0.f, 0.f);
      if ((unsigned)gh2 < (unsigned)H && (unsigned)ws2 <= (unsigned)(W - 4))
        v = *(const float4*)(y_old + (size_t)b * ybs +
                             (size_t)(cc * 8 + cil) * HW + gh2 * W + ws2);
      *(float4*)&ysl[nb][cil][rr][j * 4] = v;
    }
  };

  // stage channel-sum tile (reads s_in; s is double-buffered across steps)
  for (int i = tid; i < 340; i += 512) {
    int rr = i / 34, cl = i % 34;
    int gh2 = h0 - 1 + rr, gw2 = w0 - 1 + cl;
    float v = 0.f;
    if ((unsigned)gh2 < (unsigned)H && (unsigned)gw2 < (unsigned)W)
      v = s_in[(size_t)b * HW + gh2 * W + gw2];
    sl[rr][cl] = v;
  }
  stage(0, 0);
  __syncthreads();

  // fixed-conv increment from channel sum
  float linc[4];
#pragma unroll
  for (int p = 0; p < 4; ++p) {
    int c0 = cb + p;  // col (own-1) slot
    linc[p] =
        0.5f * (sl[sh][c0] + sl[sh][c0 + 2] + sl[sh + 2][c0] + sl[sh + 2][c0 + 2]) +
        sl[sh][c0 + 1] + sl[sh + 2][c0 + 1] + sl[sh + 1][c0] + sl[sh + 1][c0 + 2];
  }

  float acc[4][4] = {};
  float yown[4][4];  // y_old at own pixels for own 4 channels (from LDS)
  const int cc_own = g >> 1;
  const int hi = g & 1;

#pragma unroll 1
  for (int cc = 0; cc < 4; ++cc) {
    const int nb = cc & 1;
    if (cc < 3) stage(cc + 1, nb ^ 1);  // loads issue early, hide under FMAs
#pragma unroll
    for (int cil = 0; cil < 8; ++cil) {
      float yv[3][6];
#pragma unroll
      for (int dh = 0; dh < 3; ++dh) {
        const float* rowp = &ysl[nb][cil][sh + dh][0];
        float2 a = *(const float2*)(rowp + cb + 2);   // slots cb+2,cb+3
        float4 m = *(const float4*)(rowp + cb + 4);   // slots cb+4..cb+7
        float2 z = *(const float2*)(rowp + cb + 8);   // slots cb+8,cb+9
        yv[dh][0] = a.y;
        yv[dh][1] = m.x;
        yv[dh][2] = m.y;
        yv[dh][3] = m.z;
        yv[dh][4] = m.w;
        yv[dh][5] = z.x;
      }
      if (cc == cc_own && (cil >> 2) == hi) {
#pragma unroll
        for (int p = 0; p < 4; ++p) yown[cil & 3][p] = yv[1][p + 1];
      }
#pragma unroll
      for (int k = 0; k < 9; ++k) {
        const int kh = k / 3, kw = k % 3;
        float4 wk = *(const float4*)&wsl[nb][cil][k][g * 4];
        float wq[4] = {wk.x, wk.y, wk.z, wk.w};
#pragma unroll
        for (int q = 0; q < 4; ++q)
#pragma unroll
          for (int p = 0; p < 4; ++p)
            acc[q][p] = fmaf(wq[q], yv[kh][p + kw], acc[q][p]);
      }
    }
    if (cc < 3) __syncthreads();
  }

  // epilogue: state update, output write, fused channel-sum for next step
  float sp[4] = {0.f, 0.f, 0.f, 0.f};
#pragma unroll
  for (int q = 0; q < 4; ++q) {
    const int c = g * 4 + q;
    const size_t idx = (size_t)b * CHW + (size_t)c * HW + (size_t)gh * W + gwc;
    const size_t xidx = (((size_t)(b * T + t) * C + c) * H + gh) * (size_t)W + gwc;
    float4 f4 = *(const float4*)(f + idx);
    float4 l4 = *(const float4*)(l + idx);
    float4 e4 = *(const float4*)(e + idx);
    float4 x4 = *(const float4*)(x + xidx);
    const float bc = bias[c];
    float fr[4] = {f4.x, f4.y, f4.z, f4.w};
    float lr[4] = {l4.x, l4.y, l4.z, l4.w};
    float er[4] = {e4.x, e4.y, e4.z, e4.w};
    float xr[4] = {x4.x, x4.y, x4.z, x4.w};
    float fo[4], lo_[4], eo[4], yn[4];
#pragma unroll
    for (int p = 0; p < 4; ++p) {
      float fn = DF * fr[p] + acc[q][p] + bc + xr[p];
      float ln = DL * lr[p] + linc[p];
      float u = fmaf(0.5f * fn, ln, fn);
      float en = DE * er[p] + VE * yown[q][p];
      float yy = 1.f / (1.f + __expf(en - u));
      fo[p] = fn;
      lo_[p] = ln;
      eo[p] = en;
      yn[p] = yy;
      sp[p] += yy;
    }
    *(float4*)(f + idx) = make_float4(fo[0], fo[1], fo[2], fo[3]);
    *(float4*)(l + idx) = make_float4(lo_[0], lo_[1], lo_[2], lo_[3]);
    *(float4*)(e + idx) = make_float4(eo[0], eo[1], eo[2], eo[3]);
    *(float4*)(out + xidx) = make_float4(yn[0], yn[1], yn[2], yn[3]);
  }
  *(float4*)&sred[g][sidx][0] = make_float4(sp[0], sp[1], sp[2], sp[3]);
  __syncthreads();
  if (tid < 64) {
    float4 a = *(const float4*)&sred[0][tid][0];
#pragma unroll
    for (int gg = 1; gg < 8; ++gg) {
      float4 bq = *(const float4*)&sred[gg][tid][0];
      a.x += bq.x;
      a.y += bq.y;
      a.z += bq.z;
      a.w += bq.w;
    }
    *(float4*)(s_out + (size_t)b * HW + (size_t)gh * W + gwc) = a;
  }
}

}  // namespace

extern "C" void kernel_launch(void* const* d_in, const int* in_sizes, int n_in,
                              void* d_out, int out_size, void* d_ws, size_t ws_size,
                              hipStream_t stream) {
  (void)in_sizes; (void)n_in; (void)out_size; (void)ws_size;
  const float* x = (const float*)d_in[0];     // (B,T,C,H,W)
  const float* wgt = (const float*)d_in[1];   // (C,C,3,3)
  const float* bias = (const float*)d_in[2];  // (C,)
  float* out = (float*)d_out;                 // (B,T,C,H,W)

  float* ws = (float*)d_ws;
  float* f = ws;
  float* l = f + NSTATE;
  float* e = l + NSTATE;
  float* y0 = e + NSTATE;
  float* s0 = y0 + NSTATE;
  float* s1 = s0 + BHW;
  float* wtr = s1 + BHW;

  k_wtr<<<36, 256, 0, stream>>>(wgt, wtr);
  k_init<<<(int)(NSTATE / 256), 256, 0, stream>>>(f, l, e, y0, s0);

  float* s_in = s0;
  float* s_out = s1;
  for (int t = 0; t < T; ++t) {
    const float* yold = (t == 0) ? y0 : (out + (size_t)(t - 1) * CHW);
    long long ybs = (t == 0) ? (long long)CHW : (long long)T * CHW;
    k_step<<<512, 512, 0, stream>>>(x, wtr, bias, s_in, s_out, yold, ybs, f, l,
                                    e, out, t);
    float* tmp = s_in;
    s_in = s_out;
    s_out = tmp;
  }
}

// Round 3
// 3725.404 us; speedup vs baseline: 1.8982x; 1.8982x over previous
//
#include <hip/hip_runtime.h>
#include <math.h>

namespace {

constexpr int B = 8, T = 10, C = 32, H = 128, W = 128;
constexpr int HW = H * W;            // 16384
constexpr int CHW = C * HW;          // 524288
constexpr long long NSTATE = (long long)B * CHW;
constexpr int BHW = B * HW;

constexpr float DF = 0.90483741803595952f;  // exp(-0.1)
constexpr float DL = 0.36787944117144233f;  // exp(-1.0)
constexpr float DE = 0.36787944117144233f;  // exp(-1.0)
constexpr float VE = 10.0f;

// wgt[co][ci][kh][kw] -> wtr[ci][k][co]   (9216 floats)
__global__ void k_wtr(const float* __restrict__ wgt, float* __restrict__ wtr) {
  int i = blockIdx.x * 256 + threadIdx.x;
  if (i >= C * C * 9) return;
  int ci = i / 288;
  int k = (i / 32) % 9;
  int co = i & 31;
  wtr[i] = wgt[co * 288 + ci * 9 + k];
}

__global__ void k_init(float* __restrict__ f, float* __restrict__ l,
                       float* __restrict__ e, float* __restrict__ y,
                       float* __restrict__ s0) {
  long long i = (long long)blockIdx.x * 256 + threadIdx.x;
  f[i] = 0.f;
  l[i] = 0.f;
  y[i] = 0.f;
  e[i] = 10.f;  // V_E / ALPHA_E
  if (i < BHW) s0[i] = 0.f;
}

// One step. Block: 512 threads (8 waves), tile 8 rows x 32 cols, all 32 c_out.
// Wave g owns c_out = 4g..4g+3; lane: sw = strip (8x4px), sh = row (0..7).
// ci processed in 4 chunks of 8, double-buffered LDS (y-tile + weights).
// NOTE: launch_bounds(512,2) — (512,4) capped VGPRs at 64 and spilled ~6KB/thread
// to scratch (R2: WRITE_SIZE 1.64 GB/step). Keep >=128 VGPR headroom.
__launch_bounds__(512, 2)
__global__ void k_step(const float* __restrict__ x, const float* __restrict__ wtr,
                       const float* __restrict__ bias,
                       const float* __restrict__ s_in, float* __restrict__ s_out,
                       const float* __restrict__ y_old, long long ybs,
                       float* __restrict__ f, float* __restrict__ l,
                       float* __restrict__ e, float* __restrict__ out, int t) {
  __shared__ float ysl[2][8][10][40];  // [buf][ci][row][slot] slot = w-(w0-4)
  __shared__ float wsl[2][8][9][32];   // [buf][ci][k][c_out]
  __shared__ float sl[10][36];         // channel-sum tile (+halo)
  __shared__ float sred[8][64][4];     // chansum partials

  const int tid = threadIdx.x;
  const int bid = blockIdx.x;
  const int tw = bid & 3, th = (bid >> 2) & 15, b = bid >> 6;
  const int h0 = th * 8, w0 = tw * 32;
  const int g = tid >> 6, sidx = tid & 63;
  const int sw = sidx & 7, sh = sidx >> 3;
  const int cb = sw * 4;
  const int gh = h0 + sh, gwc = w0 + cb;

  auto stage = [&](int cc, int nb) {
    // weights: contiguous 2304-float chunk
    const float4* wsrc = (const float4*)(wtr + cc * 2304);
    float4* wdst = (float4*)&wsl[nb][0][0][0];
    for (int i = tid; i < 576; i += 512) wdst[i] = wsrc[i];
    // y tile: 8 ci x 10 rows x 10 aligned float4 (slots 0..39)
    for (int idx = tid; idx < 800; idx += 512) {
      int cil = idx / 100;
      int rem = idx % 100;
      int rr = rem / 10;
      int j = rem % 10;
      int gh2 = h0 - 1 + rr;
      int ws2 = w0 - 4 + 4 * j;
      float4 v = make_float4(0.f, 0.f, 0.f, 0.f);
      if ((unsigned)gh2 < (unsigned)H && (unsigned)ws2 <= (unsigned)(W - 4))
        v = *(const float4*)(y_old + (size_t)b * ybs +
                             (size_t)(cc * 8 + cil) * HW + gh2 * W + ws2);
      *(float4*)&ysl[nb][cil][rr][j * 4] = v;
    }
  };

  // stage channel-sum tile (reads s_in; s is double-buffered across steps)
  for (int i = tid; i < 340; i += 512) {
    int rr = i / 34, cl = i % 34;
    int gh2 = h0 - 1 + rr, gw2 = w0 - 1 + cl;
    float v = 0.f;
    if ((unsigned)gh2 < (unsigned)H && (unsigned)gw2 < (unsigned)W)
      v = s_in[(size_t)b * HW + gh2 * W + gw2];
    sl[rr][cl] = v;
  }
  stage(0, 0);
  __syncthreads();

  // fixed-conv increment from channel sum
  float linc[4];
#pragma unroll
  for (int p = 0; p < 4; ++p) {
    int c0 = cb + p;  // col (own-1) slot
    linc[p] =
        0.5f * (sl[sh][c0] + sl[sh][c0 + 2] + sl[sh + 2][c0] + sl[sh + 2][c0 + 2]) +
        sl[sh][c0 + 1] + sl[sh + 2][c0 + 1] + sl[sh + 1][c0] + sl[sh + 1][c0 + 2];
  }

  float acc[4][4] = {};
  float yown[4][4];  // y_old at own pixels for own 4 channels (from LDS)
  const int cc_own = g >> 1;
  const int hi = g & 1;

#pragma unroll 1
  for (int cc = 0; cc < 4; ++cc) {
    const int nb = cc & 1;
    if (cc < 3) stage(cc + 1, nb ^ 1);  // loads issue early, hide under FMAs
#pragma unroll
    for (int cil = 0; cil < 8; ++cil) {
      float yv[3][6];
#pragma unroll
      for (int dh = 0; dh < 3; ++dh) {
        const float* rowp = &ysl[nb][cil][sh + dh][0];
        float2 a = *(const float2*)(rowp + cb + 2);   // slots cb+2,cb+3
        float4 m = *(const float4*)(rowp + cb + 4);   // slots cb+4..cb+7
        float2 z = *(const float2*)(rowp + cb + 8);   // slots cb+8,cb+9
        yv[dh][0] = a.y;
        yv[dh][1] = m.x;
        yv[dh][2] = m.y;
        yv[dh][3] = m.z;
        yv[dh][4] = m.w;
        yv[dh][5] = z.x;
      }
      if (cc == cc_own && (cil >> 2) == hi) {
#pragma unroll
        for (int p = 0; p < 4; ++p) yown[cil & 3][p] = yv[1][p + 1];
      }
#pragma unroll
      for (int k = 0; k < 9; ++k) {
        const int kh = k / 3, kw = k % 3;
        float4 wk = *(const float4*)&wsl[nb][cil][k][g * 4];
        float wq[4] = {wk.x, wk.y, wk.z, wk.w};
#pragma unroll
        for (int q = 0; q < 4; ++q)
#pragma unroll
          for (int p = 0; p < 4; ++p)
            acc[q][p] = fmaf(wq[q], yv[kh][p + kw], acc[q][p]);
      }
    }
    if (cc < 3) __syncthreads();
  }

  // epilogue: state update, output write, fused channel-sum for next step
  float sp[4] = {0.f, 0.f, 0.f, 0.f};
#pragma unroll
  for (int q = 0; q < 4; ++q) {
    const int c = g * 4 + q;
    const size_t idx = (size_t)b * CHW + (size_t)c * HW + (size_t)gh * W + gwc;
    const size_t xidx = (((size_t)(b * T + t) * C + c) * H + gh) * (size_t)W + gwc;
    float4 f4 = *(const float4*)(f + idx);
    float4 l4 = *(const float4*)(l + idx);
    float4 e4 = *(const float4*)(e + idx);
    float4 x4 = *(const float4*)(x + xidx);
    const float bc = bias[c];
    float fr[4] = {f4.x, f4.y, f4.z, f4.w};
    float lr[4] = {l4.x, l4.y, l4.z, l4.w};
    float er[4] = {e4.x, e4.y, e4.z, e4.w};
    float xr[4] = {x4.x, x4.y, x4.z, x4.w};
    float fo[4], lo_[4], eo[4], yn[4];
#pragma unroll
    for (int p = 0; p < 4; ++p) {
      float fn = DF * fr[p] + acc[q][p] + bc + xr[p];
      float ln = DL * lr[p] + linc[p];
      float u = fmaf(0.5f * fn, ln, fn);
      float en = DE * er[p] + VE * yown[q][p];
      float yy = 1.f / (1.f + __expf(en - u));
      fo[p] = fn;
      lo_[p] = ln;
      eo[p] = en;
      yn[p] = yy;
      sp[p] += yy;
    }
    *(float4*)(f + idx) = make_float4(fo[0], fo[1], fo[2], fo[3]);
    *(float4*)(l + idx) = make_float4(lo_[0], lo_[1], lo_[2], lo_[3]);
    *(float4*)(e + idx) = make_float4(eo[0], eo[1], eo[2], eo[3]);
    *(float4*)(out + xidx) = make_float4(yn[0], yn[1], yn[2], yn[3]);
  }
  *(float4*)&sred[g][sidx][0] = make_float4(sp[0], sp[1], sp[2], sp[3]);
  __syncthreads();
  if (tid < 64) {
    float4 a = *(const float4*)&sred[0][tid][0];
#pragma unroll
    for (int gg = 1; gg < 8; ++gg) {
      float4 bq = *(const float4*)&sred[gg][tid][0];
      a.x += bq.x;
      a.y += bq.y;
      a.z += bq.z;
      a.w += bq.w;
    }
    *(float4*)(s_out + (size_t)b * HW + (size_t)gh * W + gwc) = a;
  }
}

}  // namespace

extern "C" void kernel_launch(void* const* d_in, const int* in_sizes, int n_in,
                              void* d_out, int out_size, void* d_ws, size_t ws_size,
                              hipStream_t stream) {
  (void)in_sizes; (void)n_in; (void)out_size; (void)ws_size;
  const float* x = (const float*)d_in[0];     // (B,T,C,H,W)
  const float* wgt = (const float*)d_in[1];   // (C,C,3,3)
  const float* bias = (const float*)d_in[2];  // (C,)
  float* out = (float*)d_out;                 // (B,T,C,H,W)

  float* ws = (float*)d_ws;
  float* f = ws;
  float* l = f + NSTATE;
  float* e = l + NSTATE;
  float* y0 = e + NSTATE;
  float* s0 = y0 + NSTATE;
  float* s1 = s0 + BHW;
  float* wtr = s1 + BHW;

  k_wtr<<<36, 256, 0, stream>>>(wgt, wtr);
  k_init<<<(int)(NSTATE / 256), 256, 0, stream>>>(f, l, e, y0, s0);

  float* s_in = s0;
  float* s_out = s1;
  for (int t = 0; t < T; ++t) {
    const float* yold = (t == 0) ? y0 : (out + (size_t)(t - 1) * CHW);
    long long ybs = (t == 0) ? (long long)CHW : (long long)T * CHW;
    k_step<<<512, 512, 0, stream>>>(x, wtr, bias, s_in, s_out, yold, ybs, f, l,
                                    e, out, t);
    float* tmp = s_in;
    s_in = s_out;
    s_out = tmp;
  }
}

// Round 4
// 828.412 us; speedup vs baseline: 8.5365x; 4.4970x over previous
//
#include <hip/hip_runtime.h>
#include <math.h>

namespace {

constexpr int B = 8, T = 10, C = 32, H = 128, W = 128;
constexpr int HW = H * W;            // 16384
constexpr int CHW = C * HW;          // 524288
constexpr long long NSTATE = (long long)B * CHW;
constexpr int BHW = B * HW;

constexpr float DF = 0.90483741803595952f;  // exp(-0.1)
constexpr float DL = 0.36787944117144233f;  // exp(-1.0)
constexpr float DE = 0.36787944117144233f;  // exp(-1.0)
constexpr float VE = 10.0f;

// wgt[co][ci][kh][kw] -> wtr[ci][k][co]   (9216 floats)
__global__ void k_wtr(const float* __restrict__ wgt, float* __restrict__ wtr) {
  int i = blockIdx.x * 256 + threadIdx.x;
  if (i >= C * C * 9) return;
  int ci = i / 288;
  int k = (i / 32) % 9;
  int co = i & 31;
  wtr[i] = wgt[co * 288 + ci * 9 + k];
}

__global__ void k_init(float* __restrict__ f, float* __restrict__ l,
                       float* __restrict__ e, float* __restrict__ y,
                       float* __restrict__ s0) {
  long long i = (long long)blockIdx.x * 256 + threadIdx.x;
  f[i] = 0.f;
  l[i] = 0.f;
  y[i] = 0.f;
  e[i] = 10.f;  // V_E / ALPHA_E
  if (i < BHW) s0[i] = 0.f;
}

// One step. 1024 blocks x 256 threads. Tile: 8 rows x 16 cols, all 32 c_out.
// Thread: strip s = tid&31 (sh=s>>2 row, sw=s&3 4-px strip), g = tid>>5 owns
// c_out 4g..4g+3. ci in 4 chunks of 8, double-buffered LDS.
// Register shape mirrors R1 (92 VGPR, no spill): SCALAR y ds_reads, float4
// broadcast weight reads, 16 fp32 accumulators. R2/R3's vectorized LDS reads +
// 512-thread epilogue demanded >128 VGPR -> 1.5 GB/step scratch spill.
__launch_bounds__(256, 4)
__global__ void k_step(const float* __restrict__ x, const float* __restrict__ wtr,
                       const float* __restrict__ bias,
                       const float* __restrict__ s_in, float* __restrict__ s_out,
                       const float* __restrict__ y_old, long long ybs,
                       float* __restrict__ f, float* __restrict__ l,
                       float* __restrict__ e, float* __restrict__ out, int t) {
  __shared__ float ysl[2][8][10][25];  // [buf][ci][row][slot]  slot = w-(w0-4)
  __shared__ float wsl[2][8][9][32];   // [buf][ci][k][c_out]
  __shared__ float sl[10][21];         // channel-sum tile (+halo), odd pad
  __shared__ float sred[8][32][4];     // chansum partials

  const int tid = threadIdx.x;
  const int bid = blockIdx.x;
  const int tw = bid & 7, th = (bid >> 3) & 15, b = bid >> 7;
  const int h0 = th * 8, w0 = tw * 16;
  const int g = tid >> 5, s = tid & 31;
  const int sh = s >> 2, sw = s & 3;
  const int cb = 4 * sw;
  const int gh = h0 + sh, gwc = w0 + cb;

  auto stage = [&](int cc, int nb) {
    // weights: contiguous 2304-float chunk, 16B-aligned rows
    const float4* wsrc = (const float4*)(wtr + cc * 2304);
    float4* wdst = (float4*)&wsl[nb][0][0][0];
    for (int i = tid; i < 576; i += 256) wdst[i] = wsrc[i];
    // y chunk: 8 ci x 10 rows x 6 float4 (24 slots), scalar LDS writes
    // (rows padded to 25 -> unaligned for b128, and padding breaks 32-bank
    //  power-of-2 striding on the read side)
    for (int idx = tid; idx < 480; idx += 256) {
      int cil = idx / 60;
      int rem = idx % 60;
      int rr = rem / 6;
      int j = rem % 6;
      int gh2 = h0 - 1 + rr;
      int ws2 = w0 - 4 + 4 * j;
      float4 v = make_float4(0.f, 0.f, 0.f, 0.f);
      if ((unsigned)gh2 < (unsigned)H && (unsigned)ws2 <= (unsigned)(W - 4))
        v = *(const float4*)(y_old + (size_t)b * ybs +
                             (size_t)(cc * 8 + cil) * HW + gh2 * W + ws2);
      float* dst = &ysl[nb][cil][rr][4 * j];
      dst[0] = v.x;
      dst[1] = v.y;
      dst[2] = v.z;
      dst[3] = v.w;
    }
  };

  // stage channel-sum tile (s double-buffered across steps)
  for (int i = tid; i < 180; i += 256) {
    int rr = i / 18, cl = i % 18;
    int gh2 = h0 - 1 + rr, gw2 = w0 - 1 + cl;
    float v = 0.f;
    if ((unsigned)gh2 < (unsigned)H && (unsigned)gw2 < (unsigned)W)
      v = s_in[(size_t)b * HW + gh2 * W + gw2];
    sl[rr][cl] = v;
  }
  stage(0, 0);
  __syncthreads();

  // fixed-conv increment: kernel [[.5,1,.5],[1,0,1],[.5,1,.5]] on channel sum
  float linc[4];
#pragma unroll
  for (int p = 0; p < 4; ++p) {
    const int c0 = cb + p;  // col (own-1) in sl
    linc[p] =
        0.5f * (sl[sh][c0] + sl[sh][c0 + 2] + sl[sh + 2][c0] + sl[sh + 2][c0 + 2]) +
        sl[sh][c0 + 1] + sl[sh + 2][c0 + 1] + sl[sh + 1][c0] + sl[sh + 1][c0 + 2];
  }

  float acc[4][4] = {};

#pragma unroll 1
  for (int cc = 0; cc < 4; ++cc) {
    const int nb = cc & 1;
    if (cc < 3) stage(cc + 1, nb ^ 1);
#pragma unroll
    for (int cil = 0; cil < 8; ++cil) {
      float yv[3][6];
#pragma unroll
      for (int dh = 0; dh < 3; ++dh)
#pragma unroll
        for (int dx = 0; dx < 6; ++dx)
          yv[dh][dx] = ysl[nb][cil][sh + dh][cb + 3 + dx];
#pragma unroll
      for (int k = 0; k < 9; ++k) {
        const int kh = k / 3, kw = k % 3;
        float4 wk = *(const float4*)&wsl[nb][cil][k][4 * g];
        float wq[4] = {wk.x, wk.y, wk.z, wk.w};
#pragma unroll
        for (int q = 0; q < 4; ++q)
#pragma unroll
          for (int p = 0; p < 4; ++p)
            acc[q][p] = fmaf(wq[q], yv[kh][p + kw], acc[q][p]);
      }
    }
    __syncthreads();
  }

  // epilogue: state update, output write, fused channel-sum for next step
  float sp[4] = {0.f, 0.f, 0.f, 0.f};
#pragma unroll
  for (int q = 0; q < 4; ++q) {
    const int c = 4 * g + q;
    const size_t idx = (size_t)b * CHW + (size_t)c * HW + (size_t)gh * W + gwc;
    const size_t yidx = (size_t)b * ybs + (size_t)c * HW + (size_t)gh * W + gwc;
    const size_t xidx = (((size_t)(b * T + t) * C + c) * H + gh) * (size_t)W + gwc;
    float4 f4 = *(const float4*)(f + idx);
    float4 l4 = *(const float4*)(l + idx);
    float4 e4 = *(const float4*)(e + idx);
    float4 x4 = *(const float4*)(x + xidx);
    float4 yo4 = *(const float4*)(y_old + yidx);
    const float bc = bias[c];
    float fr[4] = {f4.x, f4.y, f4.z, f4.w};
    float lr[4] = {l4.x, l4.y, l4.z, l4.w};
    float er[4] = {e4.x, e4.y, e4.z, e4.w};
    float xr[4] = {x4.x, x4.y, x4.z, x4.w};
    float yr[4] = {yo4.x, yo4.y, yo4.z, yo4.w};
    float fo[4], lo_[4], eo[4], yn[4];
#pragma unroll
    for (int p = 0; p < 4; ++p) {
      float fn = DF * fr[p] + acc[q][p] + bc + xr[p];
      float ln = DL * lr[p] + linc[p];
      float u = fmaf(0.5f * fn, ln, fn);
      float en = DE * er[p] + VE * yr[p];
      float yy = 1.f / (1.f + __expf(en - u));
      fo[p] = fn;
      lo_[p] = ln;
      eo[p] = en;
      yn[p] = yy;
      sp[p] += yy;
    }
    *(float4*)(f + idx) = make_float4(fo[0], fo[1], fo[2], fo[3]);
    *(float4*)(l + idx) = make_float4(lo_[0], lo_[1], lo_[2], lo_[3]);
    *(float4*)(e + idx) = make_float4(eo[0], eo[1], eo[2], eo[3]);
    *(float4*)(out + xidx) = make_float4(yn[0], yn[1], yn[2], yn[3]);
  }
  *(float4*)&sred[g][s][0] = make_float4(sp[0], sp[1], sp[2], sp[3]);
  __syncthreads();
  if (tid < 32) {
    float4 a = *(const float4*)&sred[0][tid][0];
#pragma unroll
    for (int gg = 1; gg < 8; ++gg) {
      float4 bq = *(const float4*)&sred[gg][tid][0];
      a.x += bq.x;
      a.y += bq.y;
      a.z += bq.z;
      a.w += bq.w;
    }
    const int rh = tid >> 2, rw = 4 * (tid & 3);
    *(float4*)(s_out + (size_t)b * HW + (size_t)(h0 + rh) * W + w0 + rw) = a;
  }
}

}  // namespace

extern "C" void kernel_launch(void* const* d_in, const int* in_sizes, int n_in,
                              void* d_out, int out_size, void* d_ws, size_t ws_size,
                              hipStream_t stream) {
  (void)in_sizes; (void)n_in; (void)out_size; (void)ws_size;
  const float* x = (const float*)d_in[0];     // (B,T,C,H,W)
  const float* wgt = (const float*)d_in[1];   // (C,C,3,3)
  const float* bias = (const float*)d_in[2];  // (C,)
  float* out = (float*)d_out;                 // (B,T,C,H,W)

  float* ws = (float*)d_ws;
  float* f = ws;
  float* l = f + NSTATE;
  float* e = l + NSTATE;
  float* y0 = e + NSTATE;
  float* s0 = y0 + NSTATE;
  float* s1 = s0 + BHW;
  float* wtr = s1 + BHW;

  k_wtr<<<36, 256, 0, stream>>>(wgt, wtr);
  k_init<<<(int)(NSTATE / 256), 256, 0, stream>>>(f, l, e, y0, s0);

  float* s_in = s0;
  float* s_out = s1;
  for (int t = 0; t < T; ++t) {
    const float* yold = (t == 0) ? y0 : (out + (size_t)(t - 1) * CHW);
    long long ybs = (t == 0) ? (long long)CHW : (long long)T * CHW;
    k_step<<<1024, 256, 0, stream>>>(x, wtr, bias, s_in, s_out, yold, ybs, f, l,
                                     e, out, t);
    float* tmp = s_in;
    s_in = s_out;
    s_out = tmp;
  }
}